// Round 1
// baseline (55.614 us; speedup 1.0000x reference)
//
#include <hip/hip_runtime.h>

#define BLOCK 256
#define NPB 32          // nodes per block (100000 = 3125 * 32, no tail)
#define TPG 4           // nodes per 32-lane group (8 groups * 4 = 32)
#define FEAT 128
#define HID 32
#define WROW 132        // padded weight row (16B-aligned columns, breaks worst conflicts)

__global__ __launch_bounds__(BLOCK) void dcrnn_fused(
    const float* __restrict__ x,
    const float* __restrict__ Wz, const float* __restrict__ bz,
    const float* __restrict__ Wh, const float* __restrict__ bh,
    const float* __restrict__ Wlin, const float* __restrict__ blin,
    float* __restrict__ out, int n_nodes)
{
    __shared__ float sWz[HID][WROW];   // transposed combined W_z (col-major per output)
    __shared__ float sWh[HID][WROW];
    __shared__ float sX[NPB][FEAT];
    __shared__ float sbz[HID], sbh[HID], swl[HID];
    __shared__ float sbl;

    const int tid = threadIdx.x;

    // ---- load + combine weights: Wc[k][o] = W[0,0,k,o] + W[1,0,k,o], k < 128 ----
    // W shape (2,1,160,32): [d,0,k,o] at d*5120 + k*32 + o
    for (int i = tid; i < FEAT * HID; i += BLOCK) {
        int k = i >> 5, o = i & 31;
        sWz[o][k] = Wz[i] + Wz[5120 + i];
        sWh[o][k] = Wh[i] + Wh[5120 + i];
    }
    if (tid < HID) { sbz[tid] = bz[tid]; sbh[tid] = bh[tid]; swl[tid] = Wlin[tid]; }
    if (tid == 0) sbl = blin[0];

    // ---- stage x tile (coalesced float4) ----
    const long long node0 = (long long)blockIdx.x * NPB;
    {
        const float4* xg = (const float4*)(x + node0 * FEAT);
        float4* xl = (float4*)&sX[0][0];
        const int nvec = NPB * FEAT / 4;  // 1024
        const long long maxvec = ((long long)n_nodes - node0) * (FEAT / 4);
        for (int i = tid; i < nvec; i += BLOCK)
            xl[i] = (i < maxvec) ? xg[i] : make_float4(0.f, 0.f, 0.f, 0.f);
    }
    __syncthreads();

    // ---- main GEMM: lane = output column, group handles TPG nodes ----
    const int g = tid >> 5;        // 0..7
    const int o = tid & 31;        // output column 0..31
    const int ln0 = g * TPG;       // local node base

    float accz[TPG], acch[TPG];
    #pragma unroll
    for (int t = 0; t < TPG; ++t) { accz[t] = sbz[o]; acch[t] = sbh[o]; }

    #pragma unroll 4
    for (int k = 0; k < FEAT; k += 4) {
        const float4 wz = *(const float4*)&sWz[o][k];
        const float4 wh = *(const float4*)&sWh[o][k];
        #pragma unroll
        for (int t = 0; t < TPG; ++t) {
            const float4 xv = *(const float4*)&sX[ln0 + t][k];  // broadcast read
            accz[t] += xv.x * wz.x + xv.y * wz.y + xv.z * wz.z + xv.w * wz.w;
            acch[t] += xv.x * wh.x + xv.y * wh.y + xv.z * wh.z + xv.w * wh.w;
        }
    }

    // ---- epilogue: gates, relu, W_lin reduce over the 32 lanes ----
    #pragma unroll
    for (int t = 0; t < TPG; ++t) {
        float zb   = 1.f / (1.f + __expf(-accz[t]));          // sigmoid
        float htld = 2.f / (1.f + __expf(-2.f * acch[t])) - 1.f; // tanh
        float h = (1.f - zb) * htld;
        h = h > 0.f ? h : 0.f;                                 // relu
        float v = h * swl[o];
        v += __shfl_xor(v, 16);
        v += __shfl_xor(v, 8);
        v += __shfl_xor(v, 4);
        v += __shfl_xor(v, 2);
        v += __shfl_xor(v, 1);
        if (o == 0) {
            long long node = node0 + ln0 + t;
            if (node < n_nodes) out[node] = v + sbl;
        }
    }
}

extern "C" void kernel_launch(void* const* d_in, const int* in_sizes, int n_in,
                              void* d_out, int out_size, void* d_ws, size_t ws_size,
                              hipStream_t stream) {
    // inputs: 0:x 1:edge_index(dead) 2:edge_weight(dead) 3:W_z 4:b_z 5:W_r(dead)
    //         6:b_r(dead) 7:W_h 8:b_h 9:W_lin 10:b_lin
    const float* x    = (const float*)d_in[0];
    const float* Wz   = (const float*)d_in[3];
    const float* bz   = (const float*)d_in[4];
    const float* Wh   = (const float*)d_in[7];
    const float* bh   = (const float*)d_in[8];
    const float* Wlin = (const float*)d_in[9];
    const float* blin = (const float*)d_in[10];
    float* out = (float*)d_out;

    const int n_nodes = in_sizes[0] / FEAT;
    const int grid = (n_nodes + NPB - 1) / NPB;
    dcrnn_fused<<<grid, BLOCK, 0, stream>>>(x, Wz, bz, Wh, bh, Wlin, blin, out, n_nodes);
}

// Round 2
// 22.580 us; speedup vs baseline: 2.4630x; 2.4630x over previous
//
#include <hip/hip_runtime.h>

#define FEAT 128
#define HID 32
#define NPB 64           // nodes (M rows) per block
#define BLOCK 256        // 4 waves

typedef __attribute__((ext_vector_type(8))) __bf16 bf16x8;
typedef __attribute__((ext_vector_type(8))) unsigned short ushortx8;
typedef __attribute__((ext_vector_type(4))) float floatx4;

static __device__ inline unsigned short f2bf(float f) {
    unsigned int u = __builtin_bit_cast(unsigned int, f);
    u += 0x7FFFu + ((u >> 16) & 1u);          // round-to-nearest-even
    return (unsigned short)(u >> 16);
}

static __device__ inline float fsig(float v) {
    return __builtin_amdgcn_rcpf(1.f + __expf(-v));
}
static __device__ inline float ftanh(float v) {
    // 1 - 2/(e^{2v}+1); saturates correctly for |v| large
    return 1.f - 2.f * __builtin_amdgcn_rcpf(__expf(2.f * v) + 1.f);
}

// ---- prep: Wt[n][k] = bf16( W[0,0,k,o] + W[1,0,k,o] ), n=0..63 (z cols 0-31, h cols 32-63)
__global__ void prep_weights(const float* __restrict__ Wz,
                             const float* __restrict__ Wh,
                             unsigned short* __restrict__ wt) {
    int e = blockIdx.x * blockDim.x + threadIdx.x;   // 0..8191
    if (e >= 64 * FEAT) return;
    int n = e >> 7, k = e & 127;
    const float* W = (n < HID) ? Wz : Wh;
    int o = n & 31;
    // W shape (2,1,160,32): [d,0,k,o] at d*5120 + k*32 + o  (k<128: the x-part)
    float v = W[k * HID + o] + W[5120 + k * HID + o];
    wt[e] = f2bf(v);
}

__global__ __launch_bounds__(BLOCK) void dcrnn_mfma(
    const float* __restrict__ x,
    const unsigned short* __restrict__ wt,
    const float* __restrict__ bz, const float* __restrict__ bh,
    const float* __restrict__ wl, const float* __restrict__ bl,
    float* __restrict__ out, int n_nodes)
{
    __shared__ unsigned short sX[NPB * FEAT];   // bf16, XOR-swizzled rows
    __shared__ unsigned short sW[64 * FEAT];    // bf16, XOR-swizzled rows

    const int tid = threadIdx.x;
    const long long node0 = (long long)blockIdx.x * NPB;

    // ---- stage W tile (16 KB from L2-resident ws), swizzled ----
    #pragma unroll
    for (int p = 0; p < 4; ++p) {
        int idx8 = p * BLOCK + tid;             // 0..1023 groups of 8 elems
        int row = idx8 >> 4, k0 = (idx8 & 15) * 8;
        ushortx8 v = ((const ushortx8*)wt)[idx8];
        *(ushortx8*)&sX[0] != 0; // no-op guard removed by compiler
        *(ushortx8*)&sW[row * FEAT + (k0 ^ ((row & 7) << 3))] = v;
    }
    // ---- stage X tile: fp32 global (coalesced float4 pairs) -> bf16 LDS, swizzled ----
    #pragma unroll
    for (int p = 0; p < 4; ++p) {
        int idx8 = p * BLOCK + tid;             // row = idx8>>4 (0..63), k0=(idx8&15)*8
        int row = idx8 >> 4, k0 = (idx8 & 15) * 8;
        long long node = node0 + row;
        ushortx8 v = {0, 0, 0, 0, 0, 0, 0, 0};
        if (node < n_nodes) {
            const float4 a = *(const float4*)&x[node * FEAT + k0];
            const float4 b = *(const float4*)&x[node * FEAT + k0 + 4];
            v[0] = f2bf(a.x); v[1] = f2bf(a.y); v[2] = f2bf(a.z); v[3] = f2bf(a.w);
            v[4] = f2bf(b.x); v[5] = f2bf(b.y); v[6] = f2bf(b.z); v[7] = f2bf(b.w);
        }
        *(ushortx8*)&sX[row * FEAT + (k0 ^ ((row & 7) << 3))] = v;
    }
    __syncthreads();

    // ---- MFMA: wave w owns M-rows [w*16, w*16+16); 4 N-tiles x 4 K-steps ----
    const int w  = tid >> 6;
    const int l  = tid & 63;
    const int n0 = l & 15;       // A: row within tile / B: col / C: col
    const int g  = l >> 4;       // k-group (and C row-group)

    floatx4 acc[4] = {{0,0,0,0},{0,0,0,0},{0,0,0,0},{0,0,0,0}};

    #pragma unroll
    for (int s = 0; s < 4; ++s) {
        const int k0 = s * 32 + g * 8;
        const int ar = w * 16 + n0;
        bf16x8 afrag = __builtin_bit_cast(bf16x8,
            *(const ushortx8*)&sX[ar * FEAT + (k0 ^ ((ar & 7) << 3))]);
        #pragma unroll
        for (int nt = 0; nt < 4; ++nt) {
            const int br = nt * 16 + n0;
            bf16x8 bfrag = __builtin_bit_cast(bf16x8,
                *(const ushortx8*)&sW[br * FEAT + (k0 ^ ((br & 7) << 3))]);
            acc[nt] = __builtin_amdgcn_mfma_f32_16x16x32_bf16(afrag, bfrag, acc[nt], 0, 0, 0);
        }
    }

    // ---- epilogue: gates + relu + W_lin dot (reduce over 16 lanes) ----
    const float bz0 = bz[n0], bz1 = bz[n0 + 16];
    const float bh0 = bh[n0], bh1 = bh[n0 + 16];
    const float wl0 = wl[n0], wl1 = wl[n0 + 16];
    const float blv = bl[0];

    #pragma unroll
    for (int r = 0; r < 4; ++r) {
        float z0 = fsig(acc[0][r] + bz0);
        float z1 = fsig(acc[1][r] + bz1);
        float h0 = ftanh(acc[2][r] + bh0);
        float h1 = ftanh(acc[3][r] + bh1);
        float v0 = (1.f - z0) * h0; v0 = v0 > 0.f ? v0 : 0.f;
        float v1 = (1.f - z1) * h1; v1 = v1 > 0.f ? v1 : 0.f;
        float s = v0 * wl0 + v1 * wl1;
        s += __shfl_xor(s, 1);
        s += __shfl_xor(s, 2);
        s += __shfl_xor(s, 4);
        s += __shfl_xor(s, 8);
        if (n0 == 0) {
            long long m = node0 + w * 16 + g * 4 + r;
            if (m < n_nodes) out[m] = s + blv;
        }
    }
}

extern "C" void kernel_launch(void* const* d_in, const int* in_sizes, int n_in,
                              void* d_out, int out_size, void* d_ws, size_t ws_size,
                              hipStream_t stream) {
    // inputs: 0:x 1:edge_index(dead) 2:edge_weight(dead) 3:W_z 4:b_z 5:W_r(dead)
    //         6:b_r(dead) 7:W_h 8:b_h 9:W_lin 10:b_lin
    const float* x    = (const float*)d_in[0];
    const float* Wz   = (const float*)d_in[3];
    const float* bz   = (const float*)d_in[4];
    const float* Wh   = (const float*)d_in[7];
    const float* bh   = (const float*)d_in[8];
    const float* Wlin = (const float*)d_in[9];
    const float* blin = (const float*)d_in[10];
    float* out = (float*)d_out;

    unsigned short* wt = (unsigned short*)d_ws;   // 64*128 bf16 = 16 KB

    const int n_nodes = in_sizes[0] / FEAT;

    prep_weights<<<(64 * FEAT + 255) / 256, 256, 0, stream>>>(Wz, Wh, wt);

    const int grid = (n_nodes + NPB - 1) / NPB;
    dcrnn_mfma<<<grid, BLOCK, 0, stream>>>(x, wt, bz, bh, Wlin, blin, out, n_nodes);
}

// Round 3
// 20.134 us; speedup vs baseline: 2.7623x; 1.1215x over previous
//
#include <hip/hip_runtime.h>

#define FEAT 128
#define HID 32
#define NPB 64           // nodes (M rows) per block: 3125 blocks, good load balance
#define BLOCK 256        // 4 waves

typedef __attribute__((ext_vector_type(8))) __bf16 bf16x8;
typedef __attribute__((ext_vector_type(8))) unsigned short ushortx8;
typedef __attribute__((ext_vector_type(4))) float floatx4;

static __device__ inline unsigned short f2bf(float f) {
    unsigned int u = __builtin_bit_cast(unsigned int, f);
    u += 0x7FFFu + ((u >> 16) & 1u);          // round-to-nearest-even
    return (unsigned short)(u >> 16);
}
static __device__ inline float fsig(float v) {
    return __builtin_amdgcn_rcpf(1.f + __expf(-v));
}
static __device__ inline float ftanh(float v) {
    return 1.f - 2.f * __builtin_amdgcn_rcpf(__expf(2.f * v) + 1.f);
}

__global__ __launch_bounds__(BLOCK) void dcrnn_fused1(
    const float* __restrict__ x,
    const float* __restrict__ Wz, const float* __restrict__ Wh,
    const float* __restrict__ bz, const float* __restrict__ bh,
    const float* __restrict__ wl, const float* __restrict__ bl,
    float* __restrict__ out, int n_nodes)
{
    __shared__ unsigned short sX[NPB * FEAT];   // 16 KB bf16, XOR-swizzled rows
    __shared__ unsigned short sW[64 * FEAT];    // 16 KB bf16, XOR-swizzled rows
    // total LDS = 32768 B exactly -> 5 blocks/CU

    const int tid = threadIdx.x;
    const long long node0 = (long long)blockIdx.x * NPB;

    // ---- stage X tile: fp32 global -> bf16 LDS, swizzled (issued first: HBM latency) ----
    #pragma unroll
    for (int p = 0; p < 4; ++p) {
        int idx8 = p * BLOCK + tid;             // 0..1023: row=idx8>>4, k0=(idx8&15)*8
        int row = idx8 >> 4, k0 = (idx8 & 15) * 8;
        long long node = node0 + row;
        ushortx8 v = {0, 0, 0, 0, 0, 0, 0, 0};
        if (node < n_nodes) {
            const float4 a = *(const float4*)&x[node * FEAT + k0];
            const float4 b = *(const float4*)&x[node * FEAT + k0 + 4];
            v[0] = f2bf(a.x); v[1] = f2bf(a.y); v[2] = f2bf(a.z); v[3] = f2bf(a.w);
            v[4] = f2bf(b.x); v[5] = f2bf(b.y); v[6] = f2bf(b.z); v[7] = f2bf(b.w);
        }
        *(ushortx8*)&sX[row * FEAT + (k0 ^ ((row & 7) << 3))] = v;
    }

    // ---- combine + stage weights in-block (broadcast reads, L2-hot) ----
    // W shape (2,1,160,32): [d,0,k,o] at d*5120 + k*32 + o; k<128 is the x-part.
    // sW rows 0..31 = z-gate cols, rows 32..63 = h-gate cols.
    {
        const int o4 = (tid & 7) * 4;           // output col group
        const int kb = tid >> 3;                // 0..31
        #pragma unroll
        for (int kk = kb; kk < FEAT; kk += 32) {
            const float4 z0 = *(const float4*)&Wz[kk * HID + o4];
            const float4 z1 = *(const float4*)&Wz[5120 + kk * HID + o4];
            const float4 h0 = *(const float4*)&Wh[kk * HID + o4];
            const float4 h1 = *(const float4*)&Wh[5120 + kk * HID + o4];
            const float zs[4] = {z0.x + z1.x, z0.y + z1.y, z0.z + z1.z, z0.w + z1.w};
            const float hs[4] = {h0.x + h1.x, h0.y + h1.y, h0.z + h1.z, h0.w + h1.w};
            #pragma unroll
            for (int j = 0; j < 4; ++j) {
                const int rz = o4 + j;          // 0..31
                const int rh = rz + 32;         // 32..63 ((rh&7)==(rz&7))
                sW[rz * FEAT + (kk ^ ((rz & 7) << 3))] = f2bf(zs[j]);
                sW[rh * FEAT + (kk ^ ((rh & 7) << 3))] = f2bf(hs[j]);
            }
        }
    }
    __syncthreads();

    // ---- MFMA: wave w owns M-rows [w*16, w*16+16); 4 N-tiles x 4 K-steps ----
    const int w  = tid >> 6;
    const int l  = tid & 63;
    const int n0 = l & 15;       // A: row within tile / B: col / C: col
    const int g  = l >> 4;       // k-group (and C row-group)

    floatx4 acc[4] = {{0,0,0,0},{0,0,0,0},{0,0,0,0},{0,0,0,0}};

    #pragma unroll
    for (int s = 0; s < 4; ++s) {
        const int k0 = s * 32 + g * 8;
        const int ar = w * 16 + n0;
        bf16x8 afrag = __builtin_bit_cast(bf16x8,
            *(const ushortx8*)&sX[ar * FEAT + (k0 ^ ((ar & 7) << 3))]);
        #pragma unroll
        for (int nt = 0; nt < 4; ++nt) {
            const int br = nt * 16 + n0;
            bf16x8 bfrag = __builtin_bit_cast(bf16x8,
                *(const ushortx8*)&sW[br * FEAT + (k0 ^ ((br & 7) << 3))]);
            acc[nt] = __builtin_amdgcn_mfma_f32_16x16x32_bf16(afrag, bfrag, acc[nt], 0, 0, 0);
        }
    }

    // ---- epilogue: gates + relu + W_lin dot (reduce over 16 lanes), float4 store ----
    const float bz0 = bz[n0], bz1 = bz[n0 + 16];
    const float bh0 = bh[n0], bh1 = bh[n0 + 16];
    const float wl0 = wl[n0], wl1 = wl[n0 + 16];
    const float blv = bl[0];

    float4 res;
    float* resp = &res.x;
    #pragma unroll
    for (int r = 0; r < 4; ++r) {
        float z0 = fsig(acc[0][r] + bz0);
        float z1 = fsig(acc[1][r] + bz1);
        float h0 = ftanh(acc[2][r] + bh0);
        float h1 = ftanh(acc[3][r] + bh1);
        float v0 = (1.f - z0) * h0; v0 = v0 > 0.f ? v0 : 0.f;
        float v1 = (1.f - z1) * h1; v1 = v1 > 0.f ? v1 : 0.f;
        float s = v0 * wl0 + v1 * wl1;
        s += __shfl_xor(s, 1);
        s += __shfl_xor(s, 2);
        s += __shfl_xor(s, 4);
        s += __shfl_xor(s, 8);
        resp[r] = s + blv;
    }
    if (n0 == 0) {
        // rows m..m+3; n_nodes % 4 == 0 and m % 4 == 0 -> all-or-nothing
        long long m = node0 + w * 16 + g * 4;
        if (m < n_nodes) *(float4*)&out[m] = res;
    }
}

extern "C" void kernel_launch(void* const* d_in, const int* in_sizes, int n_in,
                              void* d_out, int out_size, void* d_ws, size_t ws_size,
                              hipStream_t stream) {
    // inputs: 0:x 1:edge_index(dead) 2:edge_weight(dead) 3:W_z 4:b_z 5:W_r(dead)
    //         6:b_r(dead) 7:W_h 8:b_h 9:W_lin 10:b_lin
    const float* x    = (const float*)d_in[0];
    const float* Wz   = (const float*)d_in[3];
    const float* bz   = (const float*)d_in[4];
    const float* Wh   = (const float*)d_in[7];
    const float* bh   = (const float*)d_in[8];
    const float* Wlin = (const float*)d_in[9];
    const float* blin = (const float*)d_in[10];
    float* out = (float*)d_out;

    const int n_nodes = in_sizes[0] / FEAT;
    const int grid = (n_nodes + NPB - 1) / NPB;
    dcrnn_fused1<<<grid, BLOCK, 0, stream>>>(x, Wz, Wh, bz, bh, Wlin, blin, out, n_nodes);
}